// Round 2
// baseline (173.080 us; speedup 1.0000x reference)
//
#include <hip/hip_runtime.h>

#define NB 8
#define NT 2048
#define NC 1024
#define HD 64
#define N3 192

typedef float f32x4 __attribute__((ext_vector_type(4)));
typedef _Float16 f16x8 __attribute__((ext_vector_type(8)));
typedef short short8 __attribute__((ext_vector_type(8)));
typedef short short4v __attribute__((ext_vector_type(4)));

static __device__ __forceinline__ short f2h(float f) {
  _Float16 h = (_Float16)f;
  return __builtin_bit_cast(short, h);
}

typedef __attribute__((address_space(1))) const void* gptr1;
typedef __attribute__((address_space(3))) void* sptr3;
static __device__ __forceinline__ void gload_lds16(const void* g, void* s) {
  __builtin_amdgcn_global_load_lds((gptr1)g, (sptr3)s, 16, 0, 0);
}

// ---- prep: W[1024][192] f32 -> Wt [192][1024] f16 (transposed) ----
__launch_bounds__(256)
__global__ void prep_w(const float* __restrict__ W, short* __restrict__ Wt) {
  const int n = blockIdx.x;  // 0..191
  for (int k = threadIdx.x; k < NC; k += 256) {
    Wt[(size_t)n * NC + k] = f2h(W[(size_t)k * N3 + n]);
  }
}

// ---- qkv projection: x[16384,1024]f32 @ W + b, fp16 single-term MFMA ----
// out: Kb/Qb f16 [8][2048][64]; Vt f16 [8][64][2048]; kmax2[b] = max_row |k|^2
__launch_bounds__(256, 2)
__global__ void qkv_proj(const float* __restrict__ x, const short* __restrict__ Wt,
                         const float* __restrict__ bias, short* __restrict__ Kb,
                         short* __restrict__ Qb, short* __restrict__ Vt,
                         float* __restrict__ kmax2) {
  __shared__ short Ax[2][32 * 64];    // [buf][m][k] swizzled (4KB each)
  __shared__ short Bw[2][192 * 64];   // [buf][n][k] swizzled (24KB each)

  const int tid = threadIdx.x;
  const int lane = tid & 63;
  const int wave = tid >> 6;
  const int wr = wave >> 1, wc = wave & 1;   // wave tile: 16 m-rows x 96 n-cols
  const int r0 = blockIdx.x * 32;
  const int batch = r0 >> 11;
  const int t0 = r0 & (NT - 1);
  const int g = lane >> 4, c = lane & 15;

  // pre-swizzled per-lane source offset for B staging (bytes):
  // lane i -> row sub (i>>3), physical chunk (i&7) holds logical chunk (i&7)^(i>>3)
  const int bsub = lane >> 3;
  const size_t bgoff = (size_t)bsub * (NC * 2) + (size_t)((lane & 7) ^ bsub) * 16;

  f32x4 acc[6];
#pragma unroll
  for (int nt = 0; nt < 6; ++nt) acc[nt] = (f32x4){0.f, 0.f, 0.f, 0.f};

  float4 areg[2];

  auto stage_B = [&](int kt, int p) {   // 48 rows per wave, 6 x 1KB DMA
    const char* src = (const char*)Wt + (size_t)(wave * 48) * (NC * 2) +
                      (size_t)kt * 128 + bgoff;
    char* dst = (char*)Bw[p] + wave * 48 * 128;
#pragma unroll
    for (int j = 0; j < 6; ++j)
      gload_lds16(src + (size_t)(j * 8) * (NC * 2), dst + j * 8 * 128);
  };
  auto load_A = [&](int kt) {
    const float* xp = x + (size_t)r0 * NC + kt * 64;
#pragma unroll
    for (int i = 0; i < 2; ++i) {
      int idx = tid + 256 * i;          // 512 = 32 rows x 16 float4
      int row = idx >> 4, c4 = idx & 15;
      areg[i] = *(const float4*)(xp + (size_t)row * NC + c4 * 4);
    }
  };
  auto write_A = [&](int p) {
#pragma unroll
    for (int i = 0; i < 2; ++i) {
      int idx = tid + 256 * i;
      int row = idx >> 4, c4 = idx & 15;
      int byte = row * 128 + ((c4 * 8) ^ ((row & 7) << 4));
      float4 v = areg[i];
      short4v h;
      h[0] = f2h(v.x); h[1] = f2h(v.y); h[2] = f2h(v.z); h[3] = f2h(v.w);
      *(short4v*)((char*)Ax[p] + byte) = h;
    }
  };
  auto compute = [&](int p) {
#pragma unroll
    for (int kc = 0; kc < 2; ++kc) {
      const int arow = wr * 16 + c;
      f16x8 a = *(const f16x8*)((const char*)Ax[p] + arow * 128 +
                                ((kc * 64 + (g << 4)) ^ ((arow & 7) << 4)));
#pragma unroll
      for (int nt = 0; nt < 6; ++nt) {
        const int brow = wc * 96 + nt * 16 + c;
        f16x8 b = *(const f16x8*)((const char*)Bw[p] + brow * 128 +
                                  ((kc * 64 + (g << 4)) ^ ((brow & 7) << 4)));
        acc[nt] = __builtin_amdgcn_mfma_f32_16x16x32_f16(a, b, acc[nt], 0, 0, 0);
      }
    }
  };

  stage_B(0, 0);
  load_A(0);
  write_A(0);
  __syncthreads();
#pragma unroll 1
  for (int kt = 0; kt < 16; ++kt) {
    const int p = kt & 1;
    if (kt < 15) { stage_B(kt + 1, p ^ 1); load_A(kt + 1); }
    compute(p);
    if (kt < 15) write_A(p ^ 1);
    __syncthreads();
  }

  // epilogue. D layout: col = c (within 16-col tile), row = g*4 + i
  float bv[6];
#pragma unroll
  for (int nt = 0; nt < 6; ++nt) bv[nt] = bias[wc * 96 + nt * 16 + c];

  short* VTl = (short*)Ax[0];  // reuse 4KB: V^T tile [64 h][32 t] f16
  float knorm[4] = {0.f, 0.f, 0.f, 0.f};
#pragma unroll
  for (int nt = 0; nt < 6; ++nt) {
#pragma unroll
    for (int i = 0; i < 4; ++i) {
      int n = wc * 96 + nt * 16 + c;
      int lrow = wr * 16 + (g << 2) + i;        // 0..31 in block
      float v = acc[nt][i] + bv[nt];
      size_t tok = ((size_t)batch << 11) | (size_t)(t0 + lrow);
      if (n < 64) {
        Kb[tok * HD + n] = f2h(v);
        knorm[i] += v * v;                       // wc==0, nt<4 only
      } else if (n < 128) {
        Qb[tok * HD + (n - 64)] = f2h(v);
      } else {
        int h = n - 128;
        int byte = h * 64 + ((lrow * 2) ^ ((h & 3) << 4));
        *(short*)((char*)VTl + byte) = f2h(v);
      }
    }
  }
  if (wc == 0) {   // k-row norms: reduce over the 16 c-lanes, then atomicMax
#pragma unroll
    for (int d = 1; d < 16; d <<= 1)
#pragma unroll
      for (int i = 0; i < 4; ++i) knorm[i] += __shfl_xor(knorm[i], d);
    float mx = fmaxf(fmaxf(knorm[0], knorm[1]), fmaxf(knorm[2], knorm[3]));
    if (c == 0) atomicMax((int*)(kmax2 + batch), __float_as_int(mx));
  }
  __syncthreads();
  {  // V^T write-back: 256 chunks = 64 h-rows x 4
    int h = tid >> 2, ch = tid & 3;
    short8 v = *(const short8*)((const char*)VTl + h * 64 +
                                ((ch * 16) ^ ((h & 3) << 4)));
    *(short8*)(Vt + (((size_t)(batch * HD + h)) << 11) + (size_t)t0 + ch * 8) = v;
  }
}

// ---- flash attention: causal, hd=64. 1 wave per block, 32 q-rows, fixed-max ----
__launch_bounds__(64)
__global__ void attn(const short* __restrict__ Kb, const short* __restrict__ Qb,
                     const short* __restrict__ Vt, const float* __restrict__ kmax2,
                     float* __restrict__ out) {
  __shared__ short Vlds[2][64 * 64];  // [buf][h][s] swizzled (8KB each)
  __shared__ short Ones[16 * 64];     // row 0 = 1.0h, rows 1..15 = 0
  __shared__ short Plds[32 * 64];     // [q][s] swizzled (4KB)

  const int lane = threadIdx.x;
  const int g = lane >> 4, c = lane & 15;
  const int qt = blockIdx.x & 63;
  const int batch = blockIdx.x >> 6;
  const int q0 = qt * 32;
  const int nkv = (qt >> 1) + 1;
  const float c2 = 0.125f * 1.44269504088896340736f;  // scale * log2(e)

#pragma unroll
  for (int i = 0; i < 16; ++i) {      // init Ones block (1024 shorts)
    int idx = lane + 64 * i;          // row = i, col = lane
    Ones[idx] = (i == 0) ? (short)0x3C00 : (short)0;
  }

  // Q fragments (A layout: row = c, k = kc*32 + g*8 + j)
  f16x8 qa[2][2];
#pragma unroll
  for (int mt = 0; mt < 2; ++mt) {
    size_t base = (((size_t)batch << 11) | (size_t)(q0 + mt * 16 + c)) * HD + (g << 3);
    qa[mt][0] = *(const f16x8*)(Qb + base);
    qa[mt][1] = *(const f16x8*)(Qb + base + 32);
  }
  // fixed per-row max bound m2 = |q| * KMAX * c2, in D layout rows g*4+i
  float m2r[2][4];
  {
    const float kmaxn = sqrtf(kmax2[batch]);
#pragma unroll
    for (int mt = 0; mt < 2; ++mt) {
      float qn = 0.f;
#pragma unroll
      for (int kc = 0; kc < 2; ++kc)
#pragma unroll
        for (int j = 0; j < 8; ++j) {
          float qv = (float)qa[mt][kc][j];
          qn += qv * qv;
        }
      qn += __shfl_xor(qn, 16);
      qn += __shfl_xor(qn, 32);        // every lane: |q_row(c)|^2
#pragma unroll
      for (int i = 0; i < 4; ++i)
        m2r[mt][i] = sqrtf(__shfl(qn, (g << 2) + i)) * kmaxn * c2;
    }
  }

  f32x4 o[2][5];   // [mt][nt]; nt=4 accumulates row-sum l (ones column)
#pragma unroll
  for (int mt = 0; mt < 2; ++mt)
#pragma unroll
    for (int nt = 0; nt < 5; ++nt) o[mt][nt] = (f32x4){0.f, 0.f, 0.f, 0.f};

  f16x8 kfr[4][2];
  const short* kbp = Kb + (((size_t)batch << 11)) * HD;
  auto load_K = [&](int t) {
    const short* kp = kbp + (size_t)(t * 64) * HD;
#pragma unroll
    for (int st = 0; st < 4; ++st) {
      size_t rb = (size_t)(st * 16 + c) * HD + (g << 3);
      kfr[st][0] = *(const f16x8*)(kp + rb);
      kfr[st][1] = *(const f16x8*)(kp + rb + 32);
    }
  };
  const int vsub = lane >> 3;
  const size_t vgoff = (size_t)vsub * (NT * 2) + (size_t)((lane & 7) ^ vsub) * 16;
  const char* vbase = (const char*)(Vt + (((size_t)batch * HD) << 11));
  auto stage_V = [&](int t, int p) {   // 64 rows x 128B, 8 x 1KB DMA
    const char* src = vbase + (size_t)t * 128 + vgoff;
    char* dst = (char*)Vlds[p];
#pragma unroll
    for (int j = 0; j < 8; ++j)
      gload_lds16(src + (size_t)(j * 8) * (NT * 2), dst + j * 8 * 128);
  };

  stage_V(0, 0);
  load_K(0);
  int p = 0;
#pragma unroll 1
  for (int t = 0; t < nkv; ++t) {
    const int s0 = t * 64;
    if (t + 1 < nkv) stage_V(t + 1, p ^ 1);

    // S = Q K^T
    f32x4 s[2][4];
#pragma unroll
    for (int mt = 0; mt < 2; ++mt)
#pragma unroll
      for (int st = 0; st < 4; ++st) s[mt][st] = (f32x4){0.f, 0.f, 0.f, 0.f};
#pragma unroll
    for (int kc = 0; kc < 2; ++kc)
#pragma unroll
      for (int st = 0; st < 4; ++st) {
        s[0][st] = __builtin_amdgcn_mfma_f32_16x16x32_f16(qa[0][kc], kfr[st][kc], s[0][st], 0, 0, 0);
        s[1][st] = __builtin_amdgcn_mfma_f32_16x16x32_f16(qa[1][kc], kfr[st][kc], s[1][st], 0, 0, 0);
      }

    if (t + 1 < nkv) load_K(t + 1);

    // P = exp2(S*c2 - m2) (fixed max; masked -> 0), store f16 to Plds
    const bool diag = (s0 + 63 > q0);
#pragma unroll
    for (int mt = 0; mt < 2; ++mt)
#pragma unroll
      for (int st = 0; st < 4; ++st)
#pragma unroll
        for (int i = 0; i < 4; ++i) {
          int cg = s0 + st * 16 + c;
          int rg = q0 + mt * 16 + (g << 2) + i;
          float pv = __builtin_amdgcn_exp2f(s[mt][st][i] * c2 - m2r[mt][i]);
          if (diag && cg > rg) pv = 0.f;
          int prow = mt * 16 + (g << 2) + i;
          *(short*)((char*)Plds + prow * 128 +
                    (((st * 16 + c) * 2) ^ ((prow & 7) << 4))) = f2h(pv);
        }

    // ensure V DMA (and everything) landed before LDS reads; 1-wave block has no barrier
    asm volatile("s_waitcnt vmcnt(0)" ::: "memory");
    __builtin_amdgcn_sched_barrier(0);

    // O += P V ; l += P * 1
#pragma unroll
    for (int kc = 0; kc < 2; ++kc) {
      f16x8 pa[2];
#pragma unroll
      for (int mt = 0; mt < 2; ++mt) {
        int prow = mt * 16 + c;
        pa[mt] = *(const f16x8*)((const char*)Plds + prow * 128 +
                                 ((kc * 64 + (g << 4)) ^ ((prow & 7) << 4)));
      }
#pragma unroll
      for (int nt = 0; nt < 5; ++nt) {
        f16x8 b;
        if (nt < 4) {
          int vrow = nt * 16 + c;
          b = *(const f16x8*)((const char*)Vlds[p] + vrow * 128 +
                              ((kc * 64 + (g << 4)) ^ ((vrow & 7) << 4)));
        } else {
          b = *(const f16x8*)((const char*)Ones + c * 128 + kc * 64 + (g << 4));
        }
        o[0][nt] = __builtin_amdgcn_mfma_f32_16x16x32_f16(pa[0], b, o[0][nt], 0, 0, 0);
        o[1][nt] = __builtin_amdgcn_mfma_f32_16x16x32_f16(pa[1], b, o[1][nt], 0, 0, 0);
      }
    }
    p ^= 1;
  }

  // epilogue: out = O / l ; l lives in col 64 = tile-col 0 of nt=4 (lanes c==0)
#pragma unroll
  for (int mt = 0; mt < 2; ++mt)
#pragma unroll
    for (int i = 0; i < 4; ++i) {
      float l = __shfl(o[mt][4][i], (lane >> 4) << 4);
      float inv = 1.0f / l;
      int rg = q0 + mt * 16 + (g << 2) + i;
#pragma unroll
      for (int nt = 0; nt < 4; ++nt)
        out[(((size_t)batch << 11) | (size_t)rg) * HD + nt * 16 + c] = o[mt][nt][i] * inv;
    }
}

extern "C" void kernel_launch(void* const* d_in, const int* in_sizes, int n_in,
                              void* d_out, int out_size, void* d_ws, size_t ws_size,
                              hipStream_t stream) {
  const float* x = (const float*)d_in[0];
  const float* W = (const float*)d_in[1];
  const float* bias = (const float*)d_in[2];
  float* out = (float*)d_out;

  char* ws = (char*)d_ws;
  float* kmax2 = (float*)ws;                       // 8 f32 (32B)
  short* Wt = (short*)(ws + 256);                  // [192][1024] f16
  short* Kb = Wt + (size_t)N3 * NC;                // [8][2048][64] f16
  short* Qb = Kb + (size_t)NB * NT * HD;           // [8][2048][64] f16
  short* Vt = Qb + (size_t)NB * NT * HD;           // [8][64][2048] f16

  hipMemsetAsync(kmax2, 0, 8 * sizeof(float), stream);
  prep_w<<<N3, 256, 0, stream>>>(W, Wt);
  qkv_proj<<<512, 256, 0, stream>>>(x, Wt, bias, Kb, Qb, Vt, kmax2);
  attn<<<NB * 64, 64, 0, stream>>>(Kb, Qb, Vt, kmax2, out);
}

// Round 3
// 141.819 us; speedup vs baseline: 1.2204x; 1.2204x over previous
//
#include <hip/hip_runtime.h>

#define NB 8
#define NT 2048
#define NC 1024
#define HD 64
#define N3 192

typedef float f32x4 __attribute__((ext_vector_type(4)));
typedef _Float16 f16x8 __attribute__((ext_vector_type(8)));
typedef short short8 __attribute__((ext_vector_type(8)));
typedef short short4v __attribute__((ext_vector_type(4)));

static __device__ __forceinline__ short f2h(float f) {
  _Float16 h = (_Float16)f;
  return __builtin_bit_cast(short, h);
}

typedef __attribute__((address_space(1))) const void* gptr1;
typedef __attribute__((address_space(3))) void* sptr3;
static __device__ __forceinline__ void gload_lds16(const void* g, void* s) {
  __builtin_amdgcn_global_load_lds((gptr1)g, (sptr3)s, 16, 0, 0);
}

// ---- prep: W[1024][192] f32 -> Wt [192][1024] f16 (transposed), coalesced reads ----
__launch_bounds__(256)
__global__ void prep_w(const float* __restrict__ W, short* __restrict__ Wt) {
  const int n = threadIdx.x;
  if (n >= 192) return;
  const int k0 = blockIdx.x * 16;
  short8 v0, v1;
#pragma unroll
  for (int j = 0; j < 8; ++j) v0[j] = f2h(W[(size_t)(k0 + j) * N3 + n]);
#pragma unroll
  for (int j = 0; j < 8; ++j) v1[j] = f2h(W[(size_t)(k0 + 8 + j) * N3 + n]);
  *(short8*)(Wt + (size_t)n * NC + k0) = v0;
  *(short8*)(Wt + (size_t)n * NC + k0 + 8) = v1;
}

// ---- qkv projection: x[16384,1024]f32 @ W + b, fp16 single-term MFMA ----
__launch_bounds__(256, 2)
__global__ void qkv_proj(const float* __restrict__ x, const short* __restrict__ Wt,
                         const float* __restrict__ bias, short* __restrict__ Kb,
                         short* __restrict__ Qb, short* __restrict__ Vt,
                         float* __restrict__ kmax2) {
  __shared__ short Ax[2][32 * 64];    // [buf][m][k] swizzled (4KB each)
  __shared__ short Bw[2][192 * 64];   // [buf][n][k] swizzled (24KB each)

  const int tid = threadIdx.x;
  const int lane = tid & 63;
  const int wave = tid >> 6;
  const int wr = wave >> 1, wc = wave & 1;   // wave tile: 16 m-rows x 96 n-cols
  const int r0 = blockIdx.x * 32;
  const int batch = r0 >> 11;
  const int t0 = r0 & (NT - 1);
  const int g = lane >> 4, c = lane & 15;

  const int bsub = lane >> 3;
  const size_t bgoff = (size_t)bsub * (NC * 2) + (size_t)((lane & 7) ^ bsub) * 16;

  f32x4 acc[6];
#pragma unroll
  for (int nt = 0; nt < 6; ++nt) acc[nt] = (f32x4){0.f, 0.f, 0.f, 0.f};

  float4 areg[2];

  auto stage_B = [&](int kt, int p) {
    const char* src = (const char*)Wt + (size_t)(wave * 48) * (NC * 2) +
                      (size_t)kt * 128 + bgoff;
    char* dst = (char*)Bw[p] + wave * 48 * 128;
#pragma unroll
    for (int j = 0; j < 6; ++j)
      gload_lds16(src + (size_t)(j * 8) * (NC * 2), dst + j * 8 * 128);
  };
  auto load_A = [&](int kt) {
    const float* xp = x + (size_t)r0 * NC + kt * 64;
#pragma unroll
    for (int i = 0; i < 2; ++i) {
      int idx = tid + 256 * i;
      int row = idx >> 4, c4 = idx & 15;
      areg[i] = *(const float4*)(xp + (size_t)row * NC + c4 * 4);
    }
  };
  auto write_A = [&](int p) {
#pragma unroll
    for (int i = 0; i < 2; ++i) {
      int idx = tid + 256 * i;
      int row = idx >> 4, c4 = idx & 15;
      int byte = row * 128 + ((c4 * 8) ^ ((row & 7) << 4));
      float4 v = areg[i];
      short4v h;
      h[0] = f2h(v.x); h[1] = f2h(v.y); h[2] = f2h(v.z); h[3] = f2h(v.w);
      *(short4v*)((char*)Ax[p] + byte) = h;
    }
  };
  auto compute = [&](int p) {
#pragma unroll
    for (int kc = 0; kc < 2; ++kc) {
      const int arow = wr * 16 + c;
      f16x8 a = *(const f16x8*)((const char*)Ax[p] + arow * 128 +
                                ((kc * 64 + (g << 4)) ^ ((arow & 7) << 4)));
#pragma unroll
      for (int nt = 0; nt < 6; ++nt) {
        const int brow = wc * 96 + nt * 16 + c;
        f16x8 b = *(const f16x8*)((const char*)Bw[p] + brow * 128 +
                                  ((kc * 64 + (g << 4)) ^ ((brow & 7) << 4)));
        acc[nt] = __builtin_amdgcn_mfma_f32_16x16x32_f16(a, b, acc[nt], 0, 0, 0);
      }
    }
  };

  stage_B(0, 0);
  load_A(0);
  write_A(0);
  __syncthreads();
#pragma unroll 1
  for (int kt = 0; kt < 16; ++kt) {
    const int p = kt & 1;
    if (kt < 15) { stage_B(kt + 1, p ^ 1); load_A(kt + 1); }
    compute(p);
    if (kt < 15) write_A(p ^ 1);
    __syncthreads();
  }

  float bv[6];
#pragma unroll
  for (int nt = 0; nt < 6; ++nt) bv[nt] = bias[wc * 96 + nt * 16 + c];

  short* VTl = (short*)Ax[0];
  float knorm[4] = {0.f, 0.f, 0.f, 0.f};
#pragma unroll
  for (int nt = 0; nt < 6; ++nt) {
#pragma unroll
    for (int i = 0; i < 4; ++i) {
      int n = wc * 96 + nt * 16 + c;
      int lrow = wr * 16 + (g << 2) + i;
      float v = acc[nt][i] + bv[nt];
      size_t tok = ((size_t)batch << 11) | (size_t)(t0 + lrow);
      if (n < 64) {
        Kb[tok * HD + n] = f2h(v);
        knorm[i] += v * v;
      } else if (n < 128) {
        Qb[tok * HD + (n - 64)] = f2h(v);
      } else {
        int h = n - 128;
        int byte = h * 64 + ((lrow * 2) ^ ((h & 3) << 4));
        *(short*)((char*)VTl + byte) = f2h(v);
      }
    }
  }
  if (wc == 0) {
#pragma unroll
    for (int d = 1; d < 16; d <<= 1)
#pragma unroll
      for (int i = 0; i < 4; ++i) knorm[i] += __shfl_xor(knorm[i], d);
    float mx = fmaxf(fmaxf(knorm[0], knorm[1]), fmaxf(knorm[2], knorm[3]));
    if (c == 0) atomicMax((int*)(kmax2 + batch), __float_as_int(mx));
  }
  __syncthreads();
  {
    int h = tid >> 2, ch = tid & 3;
    short8 v = *(const short8*)((const char*)VTl + h * 64 +
                                ((ch * 16) ^ ((h & 3) << 4)));
    *(short8*)(Vt + (((size_t)(batch * HD + h)) << 11) + (size_t)t0 + ch * 8) = v;
  }
}

// ---- attention partials: 4 waves/block, 64 q-rows, KV 4-way split, fixed-max ----
// slot(b,qt,ch) holds O[64][64] f32 + l[64]; partials are additive (fixed max).
__launch_bounds__(256)
__global__ void attn_part(const short* __restrict__ Kb, const short* __restrict__ Qb,
                          const short* __restrict__ Vt, const float* __restrict__ kmax2,
                          float* __restrict__ Opart, float* __restrict__ Lpart) {
  __shared__ short Kld[2][64 * 64];   // [buf][s][h] swizzled (8KB each)
  __shared__ short Vld[2][64 * 64];   // [buf][h][s] swizzled (8KB each)
  __shared__ short Pld[4][16 * 64];   // per-wave [q][s] swizzled (2KB each)

  const int tid = threadIdx.x, lane = tid & 63, wave = tid >> 6;
  const int g = lane >> 4, c = lane & 15;
  const int bid = blockIdx.x;
  const int ch = bid & 3;
  const int qt = 31 - ((bid >> 2) & 31);   // longest-first dispatch
  const int b = bid >> 7;
  const int nkv = qt + 1;
  const int ks = ch * nkv / 4, ke = (ch + 1) * nkv / 4;
  if (ks == ke) return;
  const int q0 = qt * 64;
  const int slot = (b * 32 + qt) * 4 + ch;
  const float c2 = 0.125f * 1.44269504088896340736f;  // scale * log2(e)

  // Q fragments for this wave's 16 rows (A layout: row=c, k=kc*32+g*8+j)
  f16x8 qa[2];
  {
    size_t qbase = ((size_t)b * NT + (size_t)(q0 + wave * 16 + c)) * HD + (g << 3);
    qa[0] = *(const f16x8*)(Qb + qbase);
    qa[1] = *(const f16x8*)(Qb + qbase + 32);
  }
  // fixed per-row max bound m2 = |q| * KMAX * c2 (deterministic across chunks)
  float m2r[4];
  {
    const float kmaxn = sqrtf(kmax2[b]);
    float qn = 0.f;
#pragma unroll
    for (int kc = 0; kc < 2; ++kc)
#pragma unroll
      for (int j = 0; j < 8; ++j) {
        float qv = (float)qa[kc][j];
        qn += qv * qv;
      }
    qn += __shfl_xor(qn, 16);
    qn += __shfl_xor(qn, 32);
#pragma unroll
    for (int i = 0; i < 4; ++i)
      m2r[i] = sqrtf(__shfl(qn, (g << 2) + i)) * kmaxn * c2;
  }

  f32x4 o[5];   // nt=4 accumulates row-sum l via ones column
#pragma unroll
  for (int nt = 0; nt < 5; ++nt) o[nt] = (f32x4){0.f, 0.f, 0.f, 0.f};
  f16x8 bone;
#pragma unroll
  for (int j = 0; j < 8; ++j) bone[j] = (c == 0) ? (_Float16)1.0f : (_Float16)0.0f;

  const int sub = lane >> 3, chx = (lane & 7) ^ sub;
  const char* ksrc = (const char*)Kb + ((size_t)b * NT) * 128;   // K row pitch 128B
  const char* vsrc = (const char*)Vt + ((size_t)b * HD) * 4096;  // V^T row pitch 4096B

  auto stage = [&](int t, int p) {   // wave covers 16 K-rows + 16 V-rows
    const int s0 = t * 64;
    const char* kp = ksrc + (size_t)(s0 + wave * 16 + sub) * 128 + (size_t)chx * 16;
    const char* vp = vsrc + (size_t)(wave * 16 + sub) * 4096 + (size_t)s0 * 2 + (size_t)chx * 16;
    gload_lds16(kp, (char*)Kld[p] + (wave * 16) * 128);
    gload_lds16(kp + 8 * 128, (char*)Kld[p] + (wave * 16 + 8) * 128);
    gload_lds16(vp, (char*)Vld[p] + (wave * 16) * 128);
    gload_lds16(vp + (size_t)8 * 4096, (char*)Vld[p] + (wave * 16 + 8) * 128);
  };

  stage(ks, 0);
  __syncthreads();
  int p = 0;
#pragma unroll 1
  for (int t = ks; t < ke; ++t) {
    if (t + 1 < ke) stage(t + 1, p ^ 1);
    const int s0 = t * 64;

    // S = Q K^T
    f32x4 s[4];
#pragma unroll
    for (int st = 0; st < 4; ++st) s[st] = (f32x4){0.f, 0.f, 0.f, 0.f};
#pragma unroll
    for (int kc = 0; kc < 2; ++kc)
#pragma unroll
      for (int st = 0; st < 4; ++st) {
        int row = st * 16 + c;
        f16x8 bk = *(const f16x8*)((const char*)Kld[p] + row * 128 +
                                   ((kc * 64 + (g << 4)) ^ ((row & 7) << 4)));
        s[st] = __builtin_amdgcn_mfma_f32_16x16x32_f16(qa[kc], bk, s[st], 0, 0, 0);
      }

    // P = exp2(S*c2 - m2), mask on diagonal tile, store f16 to wave-private LDS
    const bool diag = (t == qt);
#pragma unroll
    for (int st = 0; st < 4; ++st)
#pragma unroll
      for (int i = 0; i < 4; ++i) {
        float pv = __builtin_amdgcn_exp2f(s[st][i] * c2 - m2r[i]);
        if (diag && (s0 + st * 16 + c) > (q0 + wave * 16 + (g << 2) + i)) pv = 0.f;
        int prow = (g << 2) + i;
        *(short*)((char*)Pld[wave] + prow * 128 +
                  (((st * 16 + c) * 2) ^ ((prow & 7) << 4))) = f2h(pv);
      }

    // O += P V ; l += P * ones
#pragma unroll
    for (int kc = 0; kc < 2; ++kc) {
      f16x8 pa = *(const f16x8*)((const char*)Pld[wave] + c * 128 +
                                 ((kc * 64 + (g << 4)) ^ ((c & 7) << 4)));
#pragma unroll
      for (int nt = 0; nt < 4; ++nt) {
        int vrow = nt * 16 + c;
        f16x8 bv = *(const f16x8*)((const char*)Vld[p] + vrow * 128 +
                                   ((kc * 64 + (g << 4)) ^ ((vrow & 7) << 4)));
        o[nt] = __builtin_amdgcn_mfma_f32_16x16x32_f16(pa, bv, o[nt], 0, 0, 0);
      }
      o[4] = __builtin_amdgcn_mfma_f32_16x16x32_f16(pa, bone, o[4], 0, 0, 0);
    }
    __syncthreads();
    p ^= 1;
  }

  // write partials (D layout: col=c within 16-col tile, row=g*4+i)
  float* ob = Opart + (size_t)slot * 4096 + (size_t)(wave * 16) * 64;
#pragma unroll
  for (int i = 0; i < 4; ++i) {
    int r = (g << 2) + i;
#pragma unroll
    for (int nt = 0; nt < 4; ++nt) ob[r * 64 + nt * 16 + c] = o[nt][i];
  }
  if (c == 0) {
#pragma unroll
    for (int i = 0; i < 4; ++i)
      Lpart[slot * 64 + wave * 16 + (g << 2) + i] = o[4][i];
  }
}

// ---- combine: sum live chunk partials, normalize, write out ----
__launch_bounds__(256)
__global__ void attn_comb(const float* __restrict__ Opart, const float* __restrict__ Lpart,
                          float* __restrict__ out) {
  const int qt = blockIdx.x & 31;
  const int b = blockIdx.x >> 5;
  const int nkv = qt + 1;
  const int t = threadIdx.x;
  const int base = (b * 32 + qt) * 4;

  f32x4 acc[4];
  float lsum[4];
#pragma unroll
  for (int j = 0; j < 4; ++j) { acc[j] = (f32x4){0.f, 0.f, 0.f, 0.f}; lsum[j] = 0.f; }

#pragma unroll
  for (int ch = 0; ch < 4; ++ch) {
    int ks = ch * nkv / 4, ke = (ch + 1) * nkv / 4;
    if (ks == ke) continue;
    const float* op = Opart + (size_t)(base + ch) * 4096;
    const float* lp = Lpart + (base + ch) * 64;
#pragma unroll
    for (int j = 0; j < 4; ++j) {
      int row = (t >> 4) + 16 * j;
      acc[j] += *(const f32x4*)(op + row * 64 + (t & 15) * 4);
      lsum[j] += lp[row];
    }
  }
  float* ob = out + ((size_t)b * NT + (size_t)qt * 64) * HD;
#pragma unroll
  for (int j = 0; j < 4; ++j) {
    int row = (t >> 4) + 16 * j;
    float inv = 1.0f / lsum[j];
    f32x4 v = acc[j];
    v[0] *= inv; v[1] *= inv; v[2] *= inv; v[3] *= inv;
    *(f32x4*)(ob + row * 64 + (t & 15) * 4) = v;
  }
}

extern "C" void kernel_launch(void* const* d_in, const int* in_sizes, int n_in,
                              void* d_out, int out_size, void* d_ws, size_t ws_size,
                              hipStream_t stream) {
  const float* x = (const float*)d_in[0];
  const float* W = (const float*)d_in[1];
  const float* bias = (const float*)d_in[2];
  float* out = (float*)d_out;

  char* ws = (char*)d_ws;
  float* kmax2 = (float*)ws;                       // 8 f32
  short* Wt = (short*)(ws + 256);                  // [192][1024] f16
  short* Kb = Wt + (size_t)N3 * NC;                // [8][2048][64] f16
  short* Qb = Kb + (size_t)NB * NT * HD;           // [8][2048][64] f16
  short* Vt = Qb + (size_t)NB * NT * HD;           // [8][64][2048] f16
  float* Opart = (float*)(Vt + (size_t)NB * NT * HD);   // [1024][64][64] f32
  float* Lpart = Opart + (size_t)1024 * 4096;           // [1024][64] f32

  hipMemsetAsync(kmax2, 0, 8 * sizeof(float), stream);
  prep_w<<<64, 256, 0, stream>>>(W, Wt);
  qkv_proj<<<512, 256, 0, stream>>>(x, Wt, bias, Kb, Qb, Vt, kmax2);
  attn_part<<<NB * 32 * 4, 256, 0, stream>>>(Kb, Qb, Vt, kmax2, Opart, Lpart);
  attn_comb<<<NB * 32, 256, 0, stream>>>(Opart, Lpart, out);
}